// Round 10
// baseline (24.407 us; speedup 1.0000x reference)
//
#include <hip/hip_runtime.h>
#include <math.h>

#define N      2048
#define B      8
#define NROW   16            // 8 pred rows + 8 target rows
#define CHUNKS 32
#define EPB    64            // elements ranked per K1 block
#define K1T    512
#define K2T    256
#define HALF   128           // K2 threads per row
#define EPT    16            // K2 elements per thread (128 chunks -> 7 levels)

typedef unsigned long long u64;
typedef unsigned int       u32;
typedef unsigned short     u16;

__device__ inline u32 f2key(float f) {
    u32 u = __float_as_uint(f);
    return (u & 0x80000000u) ? ~u : (u | 0x80000000u);
}
__device__ inline double wave_red(double v) {
#pragma unroll
    for (int o = 32; o > 0; o >>= 1) v += __shfl_down(v, o, 64);
    return v;
}

// K1: counting rank. Block = (row, chunk of 64). Stage row's u64 keys
// (value<<32 | index: strict total order, tie-exact — ties provably pool into
// the same PAVA block, so tie order cannot change the output) in LDS; 8
// threads per element count "greater" over one eighth (wave-uniform broadcast
// reads, pairwise for wider LDS access). Writes pos[row][i] as u16 only.
// Block 0 also (re)initializes out[0]=1.0 for K2's atomic finalize.
__global__ __launch_bounds__(K1T) void count_pos_kernel(
        const float* __restrict__ pred, const float* __restrict__ target,
        u16* __restrict__ posg, float* __restrict__ out) {
    __shared__ u64 keys[N];
    __shared__ u32 scnt[K1T];

    const int t  = threadIdx.x;
    const int rr = blockIdx.x >> 5;
    const int ch = blockIdx.x & 31;
    const float* row = (rr < B) ? pred + (size_t)rr * N
                                : target + (size_t)(rr - B) * N;

    if (blockIdx.x == 0 && t == 0) out[0] = 1.0f;

    {
        const float4 v = *(const float4*)(row + t * 4);
        const int g = t * 4;
        keys[g + 0] = ((u64)f2key(v.x) << 32) | (u32)(g + 0);
        keys[g + 1] = ((u64)f2key(v.y) << 32) | (u32)(g + 1);
        keys[g + 2] = ((u64)f2key(v.z) << 32) | (u32)(g + 2);
        keys[g + 3] = ((u64)f2key(v.w) << 32) | (u32)(g + 3);
    }
    __syncthreads();
    {
        const int e  = t & (EPB - 1);      // element within chunk
        const int h  = t >> 6;             // eighth 0..7
        const u64 Ki = keys[ch * EPB + e];
        u32 cnt = 0;
        const int j0 = h * (N / 8);
#pragma unroll 4
        for (int j = j0; j < j0 + N / 8; j += 2) {
            const u64 k0 = keys[j], k1 = keys[j + 1];
            cnt += (k0 > Ki) ? 1u : 0u;
            cnt += (k1 > Ki) ? 1u : 0u;
        }
        scnt[t] = cnt;
    }
    __syncthreads();
    if (t < EPB) {
        u32 p = 0;
#pragma unroll
        for (int k = 0; k < 8; ++k) p += scnt[t + 64 * k];
        posg[rr * N + ch * EPB + t] = (u16)p;   // descending position, unique
    }
}

// K2: block b = batch b. Threads [0,128) = pred row, [128,256) = target row.
// Loads values + u16 positions coalesced, rebuilds the sorted row by LDS
// scatter, exact PAVA (local EPT=16 fit + 7-level tree merge, double sums) in
// LDS (levels >= 1 wave-local -> LDS fence only), ranks via tiny LDS binary
// search, Pearson correlation, then atomicAdd(-corr/B) into out (K1 set 1.0).
__global__ __launch_bounds__(K2T) void pava_rank_corr_kernel(
        const float* __restrict__ pred, const float* __restrict__ target,
        const u16* __restrict__ posg, float* __restrict__ out) {
    __shared__ float  sv[2][N];        // sorted values (LDS scatter)
    __shared__ double bsum[2][N];      // PAVA block sums; aliased float* means
    __shared__ int    bcnt[2][N];      // PAVA block counts -> block starts
    __shared__ int    nb[2][HALF];
    __shared__ int    nf_sh[2];
    __shared__ float  rankt[N];        // target-row ranks (original order)
    __shared__ double red[5][2];

    const int t  = threadIdx.x;
    const int r  = t >> 7;             // 0 = pred, 1 = target
    const int tt = t & (HALF - 1);
    const int b  = blockIdx.x;
    const int rowid = (r == 0) ? b : b + B;
    const int i0 = tt * EPT;

    // ---- coalesced loads: 16 values (4x float4), 16 u16 positions (2x uint4)
    float v16[EPT];
    int   p16[EPT];
    {
        const float* row = (r == 0 ? pred : target) + (size_t)b * N;
#pragma unroll
        for (int q = 0; q < 4; ++q) {
            const float4 v = *(const float4*)(row + i0 + q * 4);
            v16[q * 4 + 0] = v.x; v16[q * 4 + 1] = v.y;
            v16[q * 4 + 2] = v.z; v16[q * 4 + 3] = v.w;
        }
        const uint4* pp = (const uint4*)(posg + (size_t)rowid * N + i0);
#pragma unroll
        for (int q = 0; q < 2; ++q) {
            const uint4 w = pp[q];
            const u32 ws4[4] = {w.x, w.y, w.z, w.w};
#pragma unroll
            for (int k = 0; k < 4; ++k) {
                p16[q * 8 + 2 * k + 0] = (int)(ws4[k] & 0xffffu);
                p16[q * 8 + 2 * k + 1] = (int)(ws4[k] >> 16);
            }
        }
#pragma unroll
        for (int e = 0; e < EPT; ++e) sv[r][p16[e]] = v16[e];
    }
    __syncthreads();

    // ---- PAVA phase 1: local non-increasing fit on own 16 sorted elements.
    // y[g] = s[g] - (N - g); block sums exact in double.
    {
        int m = 0;
#pragma unroll
        for (int e = 0; e < EPT; ++e) {
            const int g = i0 + e;
            double s = (double)sv[r][g] - (double)(N - g);
            int q = 1;
            while (m > 0) {
                const double ps = bsum[r][i0 + m - 1];
                const int    pq = bcnt[r][i0 + m - 1];
                if (ps * (double)q < s * (double)pq) { s += ps; q += pq; --m; }
                else break;
            }
            bsum[r][i0 + m] = s; bcnt[r][i0 + m] = q; ++m;
        }
        nb[r][tt] = m;
    }

    // ---- PAVA phase 2: tree merge, 7 levels over 128 chunks of 16.
    // Level 0: producers span 2 waves of the half -> __syncthreads.
    // Levels >= 1: consumers (tt<32) and producers (tt<64) are in the half's
    // wave 0 -> lockstep execution, LDS fence suffices.
    for (int l = 0; l < 7; ++l) {
        if (l == 0) __syncthreads();
        else        __threadfence_block();
        const int pairs = HALF >> (l + 1);
        if (tt < pairs) {
            const int W  = 1 << l;
            const int c  = tt << (l + 1);
            const int lb = c * EPT;
            const int rb = (c + W) * EPT;
            int m = nb[r][c];
            const int rn = nb[r][c + W];
            for (int x = 0; x < rn; ++x) {
                double s = bsum[r][rb + x]; int q = bcnt[r][rb + x];
                while (m > 0) {
                    const double ps = bsum[r][lb + m - 1];
                    const int    pq = bcnt[r][lb + m - 1];
                    if (ps * (double)q < s * (double)pq) { s += ps; q += pq; --m; }
                    else break;
                }
                bsum[r][lb + m] = s; bcnt[r][lb + m] = q; ++m;
            }
            nb[r][c] = m;
        }
    }

    // ---- compact (tt==0 produced the final list itself at level 6)
    __threadfence_block();
    if (tt == 0) {
        const int m = nb[r][0];
        float* bm = (float*)&bsum[r][0];
        int st = 0;
        for (int f = 0; f < m; ++f) {
            const int    cq = bcnt[r][f];
            const double s  = bsum[r][f];
            bcnt[r][f] = st;
            bm[f] = (float)(s / (double)cq);
            st += cq;
        }
        nf_sh[r] = m;
    }
    __syncthreads();   // publish means/starts/m to all threads

    // ---- ranks for own 16 original-order elements: v - bmean[block(pos)]
    float r16[EPT];
    {
        const int m = nf_sh[r];
        const float* bm = (const float*)&bsum[r][0];
#pragma unroll
        for (int e = 0; e < EPT; ++e) {
            const int p = p16[e];
            int lo = 0, hi = m - 1;
            while (lo < hi) {                  // last f with bstart[f] <= p
                const int mid = (lo + hi + 1) >> 1;
                if (bcnt[r][mid] <= p) lo = mid; else hi = mid - 1;
            }
            r16[e] = v16[e] - bm[lo];
        }
    }
    if (r == 1) {
#pragma unroll
        for (int e = 0; e < EPT; ++e) rankt[i0 + e] = r16[e];
    }
    __syncthreads();

    // ---- Pearson: pred-half threads pair register ranks with target ranks
    // at the same original indices from LDS. 2-wave reduction.
    if (r == 0) {
        double sp = 0, st = 0, spp = 0, stt = 0, spt = 0;
#pragma unroll
        for (int e = 0; e < EPT; ++e) {
            const double a = (double)r16[e];
            const double c = (double)rankt[i0 + e];
            sp += a; st += c; spp += a * a; stt += c * c; spt += a * c;
        }
        sp  = wave_red(sp);  st  = wave_red(st);
        spp = wave_red(spp); stt = wave_red(stt); spt = wave_red(spt);
        const int w = t >> 6, lane = t & 63;
        if (lane == 0) {
            red[0][w] = sp; red[1][w] = st; red[2][w] = spp;
            red[3][w] = stt; red[4][w] = spt;
        }
    }
    __syncthreads();
    if (t == 0) {
        double a = 0, c = 0, aa = 0, cc = 0, ac = 0;
        for (int i = 0; i < 2; ++i) {
            a += red[0][i]; c += red[1][i]; aa += red[2][i];
            cc += red[3][i]; ac += red[4][i];
        }
        const double n   = (double)N;
        const double cv  = ac - a * c / n;
        const double vp2 = aa - a * a / n;
        const double vt2 = cc - c * c / n;
        const double corr = cv / (sqrt(vp2) * sqrt(vt2) + 1e-8);
        atomicAdd(out, (float)(-corr / (double)B));
    }
}

extern "C" void kernel_launch(void* const* d_in, const int* in_sizes, int n_in,
                              void* d_out, int out_size, void* d_ws, size_t ws_size,
                              hipStream_t stream) {
    const float* pred   = (const float*)d_in[0];
    const float* target = (const float*)d_in[1];
    float* out  = (float*)d_out;
    u16*   posg = (u16*)d_ws;

    count_pos_kernel<<<NROW * CHUNKS, K1T, 0, stream>>>(pred, target, posg, out);
    pava_rank_corr_kernel<<<B, K2T, 0, stream>>>(pred, target, posg, out);
}

// Round 11
// 21.087 us; speedup vs baseline: 1.1574x; 1.1574x over previous
//
#include <hip/hip_runtime.h>
#include <math.h>

#define N      2048
#define B      8
#define NROW   16            // 8 pred rows + 8 target rows
#define CHUNKS 32
#define EPB    64            // elements ranked per K1 block
#define K1T    512
#define K2T    512
#define HALF   256           // K2 threads per row
#define EPT    8             // K2 elements per thread (256 chunks -> 8 levels)

typedef unsigned long long u64;
typedef unsigned int       u32;
typedef unsigned short     u16;

// ws layout (4-byte units): pos u16[NROW][N] @0 (64 KB); sv float[NROW][N] after
#define WS_SV  (NROW * N / 2)

__device__ inline u32 f2key(float f) {
    u32 u = __float_as_uint(f);
    return (u & 0x80000000u) ? ~u : (u | 0x80000000u);
}
__device__ inline float key2f(u32 u) {
    u = (u & 0x80000000u) ? (u & 0x7fffffffu) : ~u;
    return __uint_as_float(u);
}
__device__ inline double wave_red(double v) {
#pragma unroll
    for (int o = 32; o > 0; o >>= 1) v += __shfl_down(v, o, 64);
    return v;
}

// K1: counting rank. Block = (row, chunk of 64). Stage row's u64 keys
// (value<<32 | index: strict total order, tie-exact — ties provably pool into
// the same PAVA block, so tie order cannot change the output) in LDS; 8
// threads per element count "greater" over one eighth (wave-uniform broadcast
// reads, pairwise for wider LDS access). Writes pos[row][i] (u16) and
// sv[row][pos]=value. Block 0 also initializes out[0]=1.0 for K2's finalize.
__global__ __launch_bounds__(K1T) void count_pos_kernel(
        const float* __restrict__ pred, const float* __restrict__ target,
        u16* __restrict__ posg, float* __restrict__ svg,
        float* __restrict__ out) {
    __shared__ u64 keys[N];
    __shared__ u32 scnt[K1T];

    const int t  = threadIdx.x;
    const int rr = blockIdx.x >> 5;
    const int ch = blockIdx.x & 31;
    const float* row = (rr < B) ? pred + (size_t)rr * N
                                : target + (size_t)(rr - B) * N;

    if (blockIdx.x == 0 && t == 0) out[0] = 1.0f;

    {
        const float4 v = *(const float4*)(row + t * 4);
        const int g = t * 4;
        keys[g + 0] = ((u64)f2key(v.x) << 32) | (u32)(g + 0);
        keys[g + 1] = ((u64)f2key(v.y) << 32) | (u32)(g + 1);
        keys[g + 2] = ((u64)f2key(v.z) << 32) | (u32)(g + 2);
        keys[g + 3] = ((u64)f2key(v.w) << 32) | (u32)(g + 3);
    }
    __syncthreads();
    {
        const int e  = t & (EPB - 1);      // element within chunk
        const int h  = t >> 6;             // eighth 0..7
        const u64 Ki = keys[ch * EPB + e];
        u32 cnt = 0;
        const int j0 = h * (N / 8);
#pragma unroll 4
        for (int j = j0; j < j0 + N / 8; j += 2) {
            const u64 k0 = keys[j], k1 = keys[j + 1];
            cnt += (k0 > Ki) ? 1u : 0u;
            cnt += (k1 > Ki) ? 1u : 0u;
        }
        scnt[t] = cnt;
    }
    __syncthreads();
    if (t < EPB) {
        u32 p = 0;
#pragma unroll
        for (int k = 0; k < 8; ++k) p += scnt[t + 64 * k];
        const u64 Ki = keys[ch * EPB + t];
        posg[rr * N + ch * EPB + t] = (u16)p;          // descending pos, unique
        svg[rr * N + (int)p] = key2f((u32)(Ki >> 32)); // sorted values
    }
}

// K2: block b = batch b. Threads [0,256) = pred row, [256,512) = target row.
// All global loads hoisted to the top (overlap PAVA). Exact PAVA (local EPT=8
// fit + 8-level tree merge, double sums) in LDS; merge levels >= 2 are
// wave-local (producers+consumers in the half's wave 0) -> LDS fence only.
// Ranks via tiny LDS binary search, Pearson, atomicAdd(-corr/B) into out.
__global__ __launch_bounds__(K2T) void pava_rank_corr_kernel(
        const float* __restrict__ pred, const float* __restrict__ target,
        const u16* __restrict__ posg, const float* __restrict__ svg,
        float* __restrict__ out) {
    __shared__ double bsum[2][N];      // PAVA block sums; aliased float* means
    __shared__ int    bcnt[2][N];      // PAVA block counts -> block starts
    __shared__ int    nb[2][HALF];
    __shared__ int    nf_sh[2];
    __shared__ float  rankt[N];        // target-row ranks (original order)
    __shared__ double red[5][4];

    const int t  = threadIdx.x;
    const int r  = t >> 8;             // 0 = pred, 1 = target
    const int tt = t & (HALF - 1);
    const int b  = blockIdx.x;
    const int rowid = (r == 0) ? b : b + B;
    const int i0 = tt * EPT;

    // ---- hoisted global loads: sorted values, original values, u16 positions
    const float* svrow = svg + (size_t)rowid * N;
    const float4 sa = *(const float4*)(svrow + i0);
    const float4 sb = *(const float4*)(svrow + i0 + 4);
    const float* row = (r == 0 ? pred : target) + (size_t)b * N;
    const float4 va = *(const float4*)(row + i0);
    const float4 vb = *(const float4*)(row + i0 + 4);
    const uint4  pw = *(const uint4*)(posg + (size_t)rowid * N + i0);

    // ---- PAVA phase 1: local non-increasing fit on own 8 sorted elements.
    // y[g] = s[g] - (N - g); block sums exact in double.
    {
        const float s8[EPT] = {sa.x, sa.y, sa.z, sa.w, sb.x, sb.y, sb.z, sb.w};
        int m = 0;
#pragma unroll
        for (int e = 0; e < EPT; ++e) {
            const int g = i0 + e;
            double s = (double)s8[e] - (double)(N - g);
            int q = 1;
            while (m > 0) {
                const double ps = bsum[r][i0 + m - 1];
                const int    pq = bcnt[r][i0 + m - 1];
                if (ps * (double)q < s * (double)pq) { s += ps; q += pq; --m; }
                else break;
            }
            bsum[r][i0 + m] = s; bcnt[r][i0 + m] = q; ++m;
        }
        nb[r][tt] = m;
    }

    // ---- PAVA phase 2: tree merge, 8 levels over 256 chunks of 8.
    // Levels 0,1: producers span >1 wave -> __syncthreads. Levels >= 2:
    // active threads (tt<32) and their producers (tt<64) are both in the
    // half's wave 0 -> lockstep execution, LDS fence suffices.
    for (int l = 0; l < 8; ++l) {
        if (l < 2) __syncthreads();
        else       __threadfence_block();
        const int pairs = HALF >> (l + 1);
        if (tt < pairs) {
            const int W  = 1 << l;
            const int c  = tt << (l + 1);
            const int lb = c * EPT;
            const int rb = (c + W) * EPT;
            int m = nb[r][c];
            const int rn = nb[r][c + W];
            for (int x = 0; x < rn; ++x) {
                double s = bsum[r][rb + x]; int q = bcnt[r][rb + x];
                while (m > 0) {
                    const double ps = bsum[r][lb + m - 1];
                    const int    pq = bcnt[r][lb + m - 1];
                    if (ps * (double)q < s * (double)pq) { s += ps; q += pq; --m; }
                    else break;
                }
                bsum[r][lb + m] = s; bcnt[r][lb + m] = q; ++m;
            }
            nb[r][c] = m;
        }
    }

    // ---- compact (tt==0 is in the half's wave 0: fence suffices before)
    __threadfence_block();
    if (tt == 0) {
        const int m = nb[r][0];
        float* bm = (float*)&bsum[r][0];
        int st = 0;
        for (int f = 0; f < m; ++f) {
            const int    cq = bcnt[r][f];
            const double s  = bsum[r][f];
            bcnt[r][f] = st;
            bm[f] = (float)(s / (double)cq);
            st += cq;
        }
        nf_sh[r] = m;
    }
    __syncthreads();   // publish means/starts/m to all threads of the half

    // ---- ranks for own 8 original-order elements: v - bmean[block(pos)]
    float r8[EPT];
    {
        const float v8[EPT] = {va.x, va.y, va.z, va.w, vb.x, vb.y, vb.z, vb.w};
        const u32 pws[4] = {pw.x, pw.y, pw.z, pw.w};
        int p8[EPT];
#pragma unroll
        for (int k = 0; k < 4; ++k) {
            p8[2 * k + 0] = (int)(pws[k] & 0xffffu);
            p8[2 * k + 1] = (int)(pws[k] >> 16);
        }
        const int m = nf_sh[r];
        const float* bm = (const float*)&bsum[r][0];
#pragma unroll
        for (int e = 0; e < EPT; ++e) {
            const int p = p8[e];
            int lo = 0, hi = m - 1;
            while (lo < hi) {                  // last f with bstart[f] <= p
                const int mid = (lo + hi + 1) >> 1;
                if (bcnt[r][mid] <= p) lo = mid; else hi = mid - 1;
            }
            r8[e] = v8[e] - bm[lo];
        }
    }
    if (r == 1) {
#pragma unroll
        for (int e = 0; e < EPT; ++e) rankt[i0 + e] = r8[e];
    }
    __syncthreads();

    // ---- Pearson: pred-half threads pair register ranks with target ranks
    // at the same original indices from LDS. 4-wave reduction.
    if (r == 0) {
        double sp = 0, st = 0, spp = 0, stt = 0, spt = 0;
#pragma unroll
        for (int e = 0; e < EPT; ++e) {
            const double a = (double)r8[e];
            const double c = (double)rankt[i0 + e];
            sp += a; st += c; spp += a * a; stt += c * c; spt += a * c;
        }
        sp  = wave_red(sp);  st  = wave_red(st);
        spp = wave_red(spp); stt = wave_red(stt); spt = wave_red(spt);
        const int w = t >> 6, lane = t & 63;
        if (lane == 0) {
            red[0][w] = sp; red[1][w] = st; red[2][w] = spp;
            red[3][w] = stt; red[4][w] = spt;
        }
    }
    __syncthreads();
    if (t == 0) {
        double a = 0, c = 0, aa = 0, cc = 0, ac = 0;
        for (int i = 0; i < 4; ++i) {
            a += red[0][i]; c += red[1][i]; aa += red[2][i];
            cc += red[3][i]; ac += red[4][i];
        }
        const double n   = (double)N;
        const double cv  = ac - a * c / n;
        const double vp2 = aa - a * a / n;
        const double vt2 = cc - c * c / n;
        const double corr = cv / (sqrt(vp2) * sqrt(vt2) + 1e-8);
        atomicAdd(out, (float)(-corr / (double)B));
    }
}

extern "C" void kernel_launch(void* const* d_in, const int* in_sizes, int n_in,
                              void* d_out, int out_size, void* d_ws, size_t ws_size,
                              hipStream_t stream) {
    const float* pred   = (const float*)d_in[0];
    const float* target = (const float*)d_in[1];
    float* out  = (float*)d_out;
    u16*   posg = (u16*)d_ws;
    float* svg  = (float*)d_ws + WS_SV;

    count_pos_kernel<<<NROW * CHUNKS, K1T, 0, stream>>>(pred, target, posg, svg, out);
    pava_rank_corr_kernel<<<B, K2T, 0, stream>>>(pred, target, posg, svg, out);
}